// Round 2
// baseline (67.949 us; speedup 1.0000x reference)
//
#include <hip/hip_runtime.h>

// one_layer_net: 130-step scan over a 9x3 LUT-triangle network.
// V3: 3-step composition. Each round gathers the 8 "grandparent" states with
// 8 parallel ds_bpermute (one latency instead of three) and evaluates the
// three composed bilinear steps inline (21 fmas, depth 6). Bit-exact vs V2:
// the per-step fma sequences are identical, just inlined.
//
//   E(k, x, y) = fma(y, fma(x,k.x,k.y), fma(x,k.z,k.w))
//              = K0 + K1*x + K2*y + K3*x*y
// Round r (steps 3r,3r+1,3r+2) for lane l:
//   u1 = E(K[3r][a1], s[A(a1)], s[B(a1)])   a1 = A(a0), a0 = A(l)
//   u2 = E(K[3r][b1], s[A(b1)], s[B(b1)])   b1 = B(a0)
//   u3 = E(K[3r][a2], s[A(a2)], s[B(a2)])   a2 = A(b0), b0 = B(l)
//   u4 = E(K[3r][b2], s[A(b2)], s[B(b2)])   b2 = B(b0)
//   v1 = E(K[3r+1][a0], u1, u2)
//   v2 = E(K[3r+1][b0], u3, u4)
//   s' = E(K[3r+2][l],  v1, v2)

#define STEPS 130
#define NLUT  27   // 9 triangles x 3 LUTs
#define ROUNDS 43  // 43*3 = 129, plus 1 trailing single step

// Source wiring (indices into flat[29] = [prev.flatten(27), a, b])
__device__ __constant__ int c_idx0[9] = {3, 0, 6, 12, 9, 15, 18, 6, 15};
__device__ __constant__ int c_idx1[9] = {1, 7, 4, 19, 16, 13, 10, 22, 25};
__device__ __constant__ int c_idx2[9] = {17, 5, 11, 8, 28, 2, 27, 23, 26};

// wiring helpers: A(m)/B(m) = gather sources of lane m's update.
// B >= 27 (network inputs a,b) is folded into K0/K1 in phase 1 (K2=K3=0),
// so the gather source is a don't-care -> clamp to lane 0.
__device__ __forceinline__ int wA(int m) {
    int t = m / 3, j = m % 3;
    return (j == 0) ? c_idx1[t] : c_idx0[t];
}
__device__ __forceinline__ int wB(int m) {
    int t = m / 3, j = m % 3;
    int s = (j == 2) ? c_idx1[t] : c_idx2[t];
    return (s >= NLUT) ? 0 : s;
}

__device__ __forceinline__ float evalE(float4 k, float x, float y) {
    return fmaf(y, fmaf(x, k.x, k.y), fmaf(x, k.z, k.w));
}

__device__ __forceinline__ float bperm(int byteIdx, float v) {
    return __int_as_float(__builtin_amdgcn_ds_bpermute(byteIdx, __float_as_int(v)));
}

__global__ __launch_bounds__(1024)
void one_layer_net_kernel(const float* __restrict__ x,
                          const float* __restrict__ weights,
                          const float* __restrict__ noise,
                          float* __restrict__ out) {
    __shared__ float4 tbl[STEPS * NLUT];   // 130*27*16 = 56160 B LDS

    const int tid = threadIdx.x;
    const float a = x[0];
    const float b = x[1];

    // ---- Phase 1: parallel precompute of K-form coefficients ----
    // w' = w + |1 - |w|| * n * 0.125
    const float4* __restrict__ w4 = (const float4*)weights; // [27]
    const float4* __restrict__ n4 = (const float4*)noise;   // [130*27]
    for (int i = tid; i < STEPS * NLUT; i += 1024) {
        const int l = i % NLUT;
        float4 w = w4[l];
        float4 n = n4[i];
        float w0 = fmaf(fabsf(1.0f - fabsf(w.x)) * n.x, 0.125f, w.x);
        float w1 = fmaf(fabsf(1.0f - fabsf(w.y)) * n.y, 0.125f, w.y);
        float w2 = fmaf(fabsf(1.0f - fabsf(w.z)) * n.z, 0.125f, w.z);
        float w3 = fmaf(fabsf(1.0f - fabsf(w.w)) * n.w, 0.125f, w.w);
        float d0 = w1 - w0, s0 = w0 + w1;
        float d1 = w3 - w2, s1 = w2 + w3;
        float K3 = 0.25f * (d1 - d0);
        float K2 = 0.25f * (s1 - s0);
        float K1 = 0.25f * (d0 + d1);
        float K0 = 0.25f * (s0 + s1);
        // fold constant gB inputs: lanes 12,13 read b (flat[28]); 18,19 read a (flat[27])
        if (l == 12 || l == 13) {
            K0 = fmaf(K2, b, K0); K1 = fmaf(K3, b, K1); K2 = 0.0f; K3 = 0.0f;
        }
        if (l == 18 || l == 19) {
            K0 = fmaf(K2, a, K0); K1 = fmaf(K3, a, K1); K2 = 0.0f; K3 = 0.0f;
        }
        tbl[i] = make_float4(K3, K2, K1, K0);
    }
    __syncthreads();

    // ---- Phase 2: serial loop on wave 0 only, 3 steps per round ----
    if (tid >= 64) return;

    const int l  = tid;
    const int lc = (l < NLUT) ? l : (NLUT - 1); // lanes 27..63 mirror lane 26

    // 2-level wiring expansion (all compile-time-constant per lane)
    const int a0 = wA(lc), b0 = wB(lc);
    const int a1 = wA(a0), b1 = wB(a0);
    const int a2 = wA(b0), b2 = wB(b0);
    // leaf gather byte-indices for ds_bpermute
    const int g0 = wA(a1) << 2, g1 = wB(a1) << 2;
    const int g2 = wA(b1) << 2, g3 = wB(b1) << 2;
    const int g4 = wA(a2) << 2, g5 = wB(a2) << 2;
    const int g6 = wA(b2) << 2, g7 = wB(b2) << 2;

    // K-row base pointers; round r adds r*81 float4s (3 steps x 27)
    const float4* __restrict__ pA1 = tbl + 0 * NLUT + a1;
    const float4* __restrict__ pA2 = tbl + 0 * NLUT + b1;
    const float4* __restrict__ pA3 = tbl + 0 * NLUT + a2;
    const float4* __restrict__ pA4 = tbl + 0 * NLUT + b2;
    const float4* __restrict__ pB1 = tbl + 1 * NLUT + a0;
    const float4* __restrict__ pB2 = tbl + 1 * NLUT + b0;
    const float4* __restrict__ pC  = tbl + 2 * NLUT + lc;

    // All lanes init -1; lanes >=27 compute lane-26 duplicates (finite, never read).
    float state = -1.0f;

    #pragma unroll
    for (int r = 0; r < ROUNDS; ++r) {
        const int o = r * 3 * NLUT;        // folds to imm offsets (max 55728 B)
        // 8 parallel gathers — one cross-lane latency for 3 steps
        const float p0 = bperm(g0, state);
        const float p1 = bperm(g1, state);
        const float p2 = bperm(g2, state);
        const float p3 = bperm(g3, state);
        const float p4 = bperm(g4, state);
        const float p5 = bperm(g5, state);
        const float p6 = bperm(g6, state);
        const float p7 = bperm(g7, state);
        // K rows (state-independent; scheduler hoists/prefetches freely)
        const float4 kA1 = pA1[o], kA2 = pA2[o], kA3 = pA3[o], kA4 = pA4[o];
        const float4 kB1 = pB1[o], kB2 = pB2[o];
        const float4 kC  = pC[o];
        // composed evaluation: 21 fmas, depth 6
        const float u1 = evalE(kA1, p0, p1);
        const float u2 = evalE(kA2, p2, p3);
        const float u3 = evalE(kA3, p4, p5);
        const float u4 = evalE(kA4, p6, p7);
        const float v1 = evalE(kB1, u1, u2);
        const float v2 = evalE(kB2, u3, u4);
        state = evalE(kC, v1, v2);
    }

    // trailing step 129 (single-step path)
    {
        const float4 kc = tbl[(STEPS - 1) * NLUT + lc];
        const float gA = bperm(a0 << 2, state);
        const float gB = bperm(b0 << 2, state);
        state = evalE(kc, gA, gB);
    }

    // outputs: final[0,1] -> lane 1, final[1,2] -> lane 5, final[7,2] -> lane 23
    if (l == 1)  out[0] = state;
    if (l == 5)  out[1] = state;
    if (l == 23) out[2] = state;
}

extern "C" void kernel_launch(void* const* d_in, const int* in_sizes, int n_in,
                              void* d_out, int out_size, void* d_ws, size_t ws_size,
                              hipStream_t stream) {
    const float* x       = (const float*)d_in[0]; // [2]
    const float* weights = (const float*)d_in[1]; // [9,3,4]
    const float* noise   = (const float*)d_in[2]; // [130,9,3,4]
    float* out = (float*)d_out;                   // [3] float32
    one_layer_net_kernel<<<1, 1024, 0, stream>>>(x, weights, noise, out);
}

// Round 3
// 64.885 us; speedup vs baseline: 1.0472x; 1.0472x over previous
//
#include <hip/hip_runtime.h>

// one_layer_net: 130-step scan over a 9x3 LUT-triangle network.
// V4: V2 structure + 2-step composition. Per round (2 steps): 4 ds_bpermute
// (same rate as V2) + 3 ds_read_b128 (vs V2's 2) + 9 fmas (depth 4), but only
// ONE cross-lane latency epoch per 2 steps instead of two, and half the
// loop/waitcnt overhead. Bit-exact vs V2: identical fma sequences inlined.
//
//   E(k, x, y) = fma(y, fma(x,k.x,k.y), fma(x,k.z,k.w))
// Round r (steps 2r, 2r+1) for lane l, with a0=A(l), b0=B(l):
//   u1 = E(K[2r][a0], s[A(a0)], s[B(a0)])
//   u2 = E(K[2r][b0], s[A(b0)], s[B(b0)])
//   s' = E(K[2r+1][l], u1, u2)

#define STEPS 130
#define NLUT  27   // 9 triangles x 3 LUTs
#define ROUNDS 65  // 65*2 = 130, no tail

// Source wiring (indices into flat[29] = [prev.flatten(27), a, b])
__device__ __constant__ int c_idx0[9] = {3, 0, 6, 12, 9, 15, 18, 6, 15};
__device__ __constant__ int c_idx1[9] = {1, 7, 4, 19, 16, 13, 10, 22, 25};
__device__ __constant__ int c_idx2[9] = {17, 5, 11, 8, 28, 2, 27, 23, 26};

// wiring helpers: A(m)/B(m) = gather sources of lane m's update.
// B >= 27 (network inputs a,b) is folded into K0/K1 of row m in phase 1
// (K2=K3=0), so the gather source is a don't-care -> clamp to lane 0.
// The clamp is always paired with row K[m], preserving correctness under
// composition.
__device__ __forceinline__ int wA(int m) {
    int t = m / 3, j = m % 3;
    return (j == 0) ? c_idx1[t] : c_idx0[t];
}
__device__ __forceinline__ int wB(int m) {
    int t = m / 3, j = m % 3;
    int s = (j == 2) ? c_idx1[t] : c_idx2[t];
    return (s >= NLUT) ? 0 : s;
}

__device__ __forceinline__ float evalE(float4 k, float x, float y) {
    return fmaf(y, fmaf(x, k.x, k.y), fmaf(x, k.z, k.w));
}

__device__ __forceinline__ float bperm(int byteIdx, float v) {
    return __int_as_float(__builtin_amdgcn_ds_bpermute(byteIdx, __float_as_int(v)));
}

__global__ __launch_bounds__(1024)
void one_layer_net_kernel(const float* __restrict__ x,
                          const float* __restrict__ weights,
                          const float* __restrict__ noise,
                          float* __restrict__ out) {
    __shared__ float4 tbl[STEPS * NLUT];   // 130*27*16 = 56160 B LDS

    const int tid = threadIdx.x;
    const float a = x[0];
    const float b = x[1];

    // ---- Phase 1: parallel precompute of K-form coefficients ----
    // w' = w + |1 - |w|| * n * 0.125
    // E coefficients: K3=0.25*((w3-w2)-(w1-w0)), K2=0.25*((w2+w3)-(w0+w1)),
    //                 K1=0.25*((w1-w0)+(w3-w2)), K0=0.25*(w0+w1+w2+w3)
    const float4* __restrict__ w4 = (const float4*)weights; // [27]
    const float4* __restrict__ n4 = (const float4*)noise;   // [130*27]
    for (int i = tid; i < STEPS * NLUT; i += 1024) {
        const int l = i % NLUT;
        float4 w = w4[l];
        float4 n = n4[i];
        float w0 = fmaf(fabsf(1.0f - fabsf(w.x)) * n.x, 0.125f, w.x);
        float w1 = fmaf(fabsf(1.0f - fabsf(w.y)) * n.y, 0.125f, w.y);
        float w2 = fmaf(fabsf(1.0f - fabsf(w.z)) * n.z, 0.125f, w.z);
        float w3 = fmaf(fabsf(1.0f - fabsf(w.w)) * n.w, 0.125f, w.w);
        float d0 = w1 - w0, s0 = w0 + w1;
        float d1 = w3 - w2, s1 = w2 + w3;
        float K3 = 0.25f * (d1 - d0);
        float K2 = 0.25f * (s1 - s0);
        float K1 = 0.25f * (d0 + d1);
        float K0 = 0.25f * (s0 + s1);
        // fold constant gB inputs: lanes 12,13 read b (flat[28]); 18,19 read a (flat[27])
        if (l == 12 || l == 13) {
            K0 = fmaf(K2, b, K0); K1 = fmaf(K3, b, K1); K2 = 0.0f; K3 = 0.0f;
        }
        if (l == 18 || l == 19) {
            K0 = fmaf(K2, a, K0); K1 = fmaf(K3, a, K1); K2 = 0.0f; K3 = 0.0f;
        }
        tbl[i] = make_float4(K3, K2, K1, K0);
    }
    __syncthreads();

    // ---- Phase 2: serial loop on wave 0 only, 2 steps per round ----
    if (tid >= 64) return;

    const int l  = tid;
    const int lc = (l < NLUT) ? l : (NLUT - 1); // lanes 27..63 mirror lane 26

    // 1-level wiring expansion (all compile-time-constant per lane)
    const int a0 = wA(lc), b0 = wB(lc);
    // leaf gather byte-indices for ds_bpermute (4 per round == 2 per step)
    const int g0 = wA(a0) << 2, g1 = wB(a0) << 2;
    const int g2 = wA(b0) << 2, g3 = wB(b0) << 2;

    // K-row base pointers; round r adds r*54 float4s (2 steps x 27)
    const float4* __restrict__ pA = tbl + 0 * NLUT + a0;
    const float4* __restrict__ pB = tbl + 0 * NLUT + b0;
    const float4* __restrict__ pC = tbl + 1 * NLUT + lc;

    // All lanes init -1; lanes >=27 compute lane-26 duplicates (finite, never read).
    float state = -1.0f;

    #pragma unroll
    for (int r = 0; r < ROUNDS; ++r) {
        const int o = r * 2 * NLUT;        // folds to imm offsets (max 56144 B)
        // 4 parallel gathers — one cross-lane latency epoch for 2 steps
        const float q0 = bperm(g0, state);
        const float q1 = bperm(g1, state);
        const float q2 = bperm(g2, state);
        const float q3 = bperm(g3, state);
        // K rows (state-independent; scheduler hoists/prefetches freely)
        const float4 kA = pA[o];
        const float4 kB = pB[o];
        const float4 kC = pC[o];
        // composed evaluation: 9 fmas, depth 4
        const float u1 = evalE(kA, q0, q1);
        const float u2 = evalE(kB, q2, q3);
        state = evalE(kC, u1, u2);
    }

    // outputs: final[0,1] -> lane 1, final[1,2] -> lane 5, final[7,2] -> lane 23
    if (l == 1)  out[0] = state;
    if (l == 5)  out[1] = state;
    if (l == 23) out[2] = state;
}

extern "C" void kernel_launch(void* const* d_in, const int* in_sizes, int n_in,
                              void* d_out, int out_size, void* d_ws, size_t ws_size,
                              hipStream_t stream) {
    const float* x       = (const float*)d_in[0]; // [2]
    const float* weights = (const float*)d_in[1]; // [9,3,4]
    const float* noise   = (const float*)d_in[2]; // [130,9,3,4]
    float* out = (float*)d_out;                   // [3] float32
    one_layer_net_kernel<<<1, 1024, 0, stream>>>(x, weights, noise, out);
}

// Round 4
// 64.371 us; speedup vs baseline: 1.0556x; 1.0080x over previous
//
#include <hip/hip_runtime.h>

// one_layer_net: 130-step scan over a 9x3 LUT-triangle network.
// V5: V4 (2-step composition) + one-round-ahead K prefetch. LDS completion
// (lgkmcnt) is in-order, so issuing NEXT round's 3 ds_read_b128 BEFORE this
// round's 4 ds_bpermute means the reads retire strictly before the bperms the
// fma chain waits on -> the K rows come off the critical path entirely.
// Per-round dependent chain: state -> bperm(L) -> 4-deep fma -> state.
// Bit-exact vs V2/V4: identical fma sequences, identical values.
//
//   E(k, x, y) = fma(y, fma(x,k.x,k.y), fma(x,k.z,k.w))
// Round r (steps 2r, 2r+1) for lane l, with a0=A(l), b0=B(l):
//   u1 = E(K[2r][a0], s[A(a0)], s[B(a0)])
//   u2 = E(K[2r][b0], s[A(b0)], s[B(b0)])
//   s' = E(K[2r+1][l], u1, u2)

#define STEPS 130
#define NLUT  27   // 9 triangles x 3 LUTs
#define ROUNDS 65  // 65*2 = 130, no tail

// Source wiring (indices into flat[29] = [prev.flatten(27), a, b])
__device__ __constant__ int c_idx0[9] = {3, 0, 6, 12, 9, 15, 18, 6, 15};
__device__ __constant__ int c_idx1[9] = {1, 7, 4, 19, 16, 13, 10, 22, 25};
__device__ __constant__ int c_idx2[9] = {17, 5, 11, 8, 28, 2, 27, 23, 26};

// wiring helpers: A(m)/B(m) = gather sources of lane m's update.
// B >= 27 (network inputs a,b) is folded into K0/K1 of row m in phase 1
// (K2=K3=0), so the gather source is a don't-care -> clamp to lane 0.
__device__ __forceinline__ int wA(int m) {
    int t = m / 3, j = m % 3;
    return (j == 0) ? c_idx1[t] : c_idx0[t];
}
__device__ __forceinline__ int wB(int m) {
    int t = m / 3, j = m % 3;
    int s = (j == 2) ? c_idx1[t] : c_idx2[t];
    return (s >= NLUT) ? 0 : s;
}

__device__ __forceinline__ float evalE(float4 k, float x, float y) {
    return fmaf(y, fmaf(x, k.x, k.y), fmaf(x, k.z, k.w));
}

__device__ __forceinline__ float bperm(int byteIdx, float v) {
    return __int_as_float(__builtin_amdgcn_ds_bpermute(byteIdx, __float_as_int(v)));
}

__global__ __launch_bounds__(1024)
void one_layer_net_kernel(const float* __restrict__ x,
                          const float* __restrict__ weights,
                          const float* __restrict__ noise,
                          float* __restrict__ out) {
    __shared__ float4 tbl[STEPS * NLUT];   // 130*27*16 = 56160 B LDS

    const int tid = threadIdx.x;
    const float a = x[0];
    const float b = x[1];

    // ---- Phase 1: parallel precompute of K-form coefficients ----
    // w' = w + |1 - |w|| * n * 0.125
    // E coefficients: K3=0.25*((w3-w2)-(w1-w0)), K2=0.25*((w2+w3)-(w0+w1)),
    //                 K1=0.25*((w1-w0)+(w3-w2)), K0=0.25*(w0+w1+w2+w3)
    const float4* __restrict__ w4 = (const float4*)weights; // [27]
    const float4* __restrict__ n4 = (const float4*)noise;   // [130*27]
    for (int i = tid; i < STEPS * NLUT; i += 1024) {
        const int l = i % NLUT;
        float4 w = w4[l];
        float4 n = n4[i];
        float w0 = fmaf(fabsf(1.0f - fabsf(w.x)) * n.x, 0.125f, w.x);
        float w1 = fmaf(fabsf(1.0f - fabsf(w.y)) * n.y, 0.125f, w.y);
        float w2 = fmaf(fabsf(1.0f - fabsf(w.z)) * n.z, 0.125f, w.z);
        float w3 = fmaf(fabsf(1.0f - fabsf(w.w)) * n.w, 0.125f, w.w);
        float d0 = w1 - w0, s0 = w0 + w1;
        float d1 = w3 - w2, s1 = w2 + w3;
        float K3 = 0.25f * (d1 - d0);
        float K2 = 0.25f * (s1 - s0);
        float K1 = 0.25f * (d0 + d1);
        float K0 = 0.25f * (s0 + s1);
        // fold constant gB inputs: lanes 12,13 read b (flat[28]); 18,19 read a (flat[27])
        if (l == 12 || l == 13) {
            K0 = fmaf(K2, b, K0); K1 = fmaf(K3, b, K1); K2 = 0.0f; K3 = 0.0f;
        }
        if (l == 18 || l == 19) {
            K0 = fmaf(K2, a, K0); K1 = fmaf(K3, a, K1); K2 = 0.0f; K3 = 0.0f;
        }
        tbl[i] = make_float4(K3, K2, K1, K0);
    }
    __syncthreads();

    // ---- Phase 2: serial loop on wave 0 only, 2 steps per round ----
    if (tid >= 64) return;

    const int l  = tid;
    const int lc = (l < NLUT) ? l : (NLUT - 1); // lanes 27..63 mirror lane 26

    // 1-level wiring expansion (all compile-time-constant per lane)
    const int a0 = wA(lc), b0 = wB(lc);
    // leaf gather byte-indices for ds_bpermute (4 per round == 2 per step)
    const int g0 = wA(a0) << 2, g1 = wB(a0) << 2;
    const int g2 = wA(b0) << 2, g3 = wB(b0) << 2;

    // K-row base pointers; round r adds r*54 float4s (2 steps x 27)
    const float4* __restrict__ pA = tbl + 0 * NLUT + a0;
    const float4* __restrict__ pB = tbl + 0 * NLUT + b0;
    const float4* __restrict__ pC = tbl + 1 * NLUT + lc;

    // All lanes init -1; lanes >=27 compute lane-26 duplicates (finite, never read).
    float state = -1.0f;

    // round-0 K rows loaded up front; thereafter prefetched one round ahead
    float4 kA = pA[0], kB = pB[0], kC = pC[0];

    #pragma unroll
    for (int r = 0; r < ROUNDS; ++r) {
        // Issue NEXT round's K reads FIRST: in-order lgkmcnt retires them
        // before this round's bperms, so they never extend the critical path.
        const int on = ((r + 1 < ROUNDS) ? (r + 1) : r) * 2 * NLUT;
        const float4 kAn = pA[on];
        const float4 kBn = pB[on];
        const float4 kCn = pC[on];
        // 4 parallel gathers — one cross-lane latency epoch for 2 steps
        const float q0 = bperm(g0, state);
        const float q1 = bperm(g1, state);
        const float q2 = bperm(g2, state);
        const float q3 = bperm(g3, state);
        // composed evaluation: 9 fmas, depth 4
        const float u1 = evalE(kA, q0, q1);
        const float u2 = evalE(kB, q2, q3);
        state = evalE(kC, u1, u2);
        kA = kAn; kB = kBn; kC = kCn;
    }

    // outputs: final[0,1] -> lane 1, final[1,2] -> lane 5, final[7,2] -> lane 23
    if (l == 1)  out[0] = state;
    if (l == 5)  out[1] = state;
    if (l == 23) out[2] = state;
}

extern "C" void kernel_launch(void* const* d_in, const int* in_sizes, int n_in,
                              void* d_out, int out_size, void* d_ws, size_t ws_size,
                              hipStream_t stream) {
    const float* x       = (const float*)d_in[0]; // [2]
    const float* weights = (const float*)d_in[1]; // [9,3,4]
    const float* noise   = (const float*)d_in[2]; // [130,9,3,4]
    float* out = (float*)d_out;                   // [3] float32
    one_layer_net_kernel<<<1, 1024, 0, stream>>>(x, weights, noise, out);
}